// Round 11
// baseline (1442.473 us; speedup 1.0000x reference)
//
#include <hip/hip_runtime.h>
#include <cstdint>
#include <cstddef>

#define NB 32      // batch
#define NT 2000    // timesteps
#define NI 256     // input dim
#define NN 512     // neurons
#define M_TOT (NB * NT)   // 64000 rows of the input GEMM

typedef float f32x4 __attribute__((ext_vector_type(4)));

// ---------------- transpose R -> Rt (Rt[j][n] = R[n][j]) ----------------
__global__ void transpose_R(const float* __restrict__ R, float* __restrict__ Rt) {
    int idx = blockIdx.x * blockDim.x + threadIdx.x;
    if (idx >= NN * NN) return;
    int j = idx >> 9;          // Rt row
    int n = idx & (NN - 1);    // Rt col (coalesced write)
    Rt[idx] = R[n * NN + j];
}

// ---------------- GEMM: cur[m][n] = sum_k x[m][k]*W[n][k] + bias[n] ----------------
// 128x128 tile, BK=16, 256 threads, 8x8 per thread. (unchanged from passing round-6)
#define GBM 128
#define GBN 128
#define GBK 16
__global__ __launch_bounds__(256) void gemm_xw(const float* __restrict__ A,
                                               const float* __restrict__ Wt,
                                               const float* __restrict__ bias,
                                               float* __restrict__ C) {
    __shared__ float As[GBK][GBM];
    __shared__ float Bs[GBK][GBN];
    const int tid = threadIdx.x;
    const int bm = blockIdx.x * GBM;
    const int bn = blockIdx.y * GBN;
    const int tx = tid & 15, ty = tid >> 4;      // 16x16 thread grid
    const int lrow = tid >> 1;                   // 0..127
    const int lk = (tid & 1) * 8;                // 0 or 8
    float acc[8][8] = {};
    const float* Arow = A + (size_t)(bm + lrow) * NI + lk;
    const float* Brow = Wt + (size_t)(bn + lrow) * NI + lk;
    for (int k0 = 0; k0 < NI; k0 += GBK) {
        float4 a0 = *(const float4*)(Arow + k0);
        float4 a1 = *(const float4*)(Arow + k0 + 4);
        float4 b0 = *(const float4*)(Brow + k0);
        float4 b1 = *(const float4*)(Brow + k0 + 4);
        __syncthreads();
        As[lk + 0][lrow] = a0.x; As[lk + 1][lrow] = a0.y;
        As[lk + 2][lrow] = a0.z; As[lk + 3][lrow] = a0.w;
        As[lk + 4][lrow] = a1.x; As[lk + 5][lrow] = a1.y;
        As[lk + 6][lrow] = a1.z; As[lk + 7][lrow] = a1.w;
        Bs[lk + 0][lrow] = b0.x; Bs[lk + 1][lrow] = b0.y;
        Bs[lk + 2][lrow] = b0.z; Bs[lk + 3][lrow] = b0.w;
        Bs[lk + 4][lrow] = b1.x; Bs[lk + 5][lrow] = b1.y;
        Bs[lk + 6][lrow] = b1.z; Bs[lk + 7][lrow] = b1.w;
        __syncthreads();
        #pragma unroll
        for (int k = 0; k < GBK; ++k) {
            float4 av0 = *(const float4*)&As[k][ty * 8];
            float4 av1 = *(const float4*)&As[k][ty * 8 + 4];
            float4 bv0 = *(const float4*)&Bs[k][tx * 8];
            float4 bv1 = *(const float4*)&Bs[k][tx * 8 + 4];
            float a_[8] = {av0.x, av0.y, av0.z, av0.w, av1.x, av1.y, av1.z, av1.w};
            float b_[8] = {bv0.x, bv0.y, bv0.z, bv0.w, bv1.x, bv1.y, bv1.z, bv1.w};
            #pragma unroll
            for (int i = 0; i < 8; ++i)
                #pragma unroll
                for (int j = 0; j < 8; ++j)
                    acc[i][j] += a_[i] * b_[j];
        }
    }
    #pragma unroll
    for (int i = 0; i < 8; ++i) {
        const int row = bm + ty * 8 + i;
        #pragma unroll
        for (int j = 0; j < 8; ++j) {
            const int col = bn + tx * 8 + j;
            C[(size_t)row * NN + col] = acc[i][j] + bias[col];
        }
    }
}

// ---------------- wave-synchronous LIF scan: 1 wave per batch element ----------------
// Head-of-mask loads forced into flight with volatile inline asm (16 back-to-back
// global_load_dwordx4, single s_waitcnt vmcnt(0), sched_barrier fence). hipcc
// refused to do this from C (rounds 9/10: rolling load->wait groups, VGPR 80).
// Accumulation order is bit-identical to the passing kernels (e=0..7, bits asc).

#define UPD(C_, R_, DU_, ODU_, DW_, ODW_, A_, B_, U_, W_, Z_) do {               \
    float cc_   = __fadd_rn((C_), (R_));                                         \
    float unew_ = __fadd_rn(__fmul_rn((DU_), (U_)),                              \
                            __fmul_rn((ODU_), __fsub_rn(cc_, (W_))));            \
    float zn_   = (__fsub_rn(unew_, 1.0f) > 0.0f) ? 1.0f : 0.0f;                 \
    float s_    = __fadd_rn(__fmul_rn((A_), (U_)), __fmul_rn((B_), (Z_)));       \
    float wnew_ = __fadd_rn(__fmul_rn((DW_), (W_)),                              \
                            __fmul_rn(__fmul_rn((ODW_), s_), 120.0f));           \
    (U_) = __fmul_rn(unew_, __fsub_rn(1.0f, zn_));                               \
    (W_) = wnew_;                                                                \
    (Z_) = zn_;                                                                  \
} while (0)

// issue a 32B head row (two dwordx4) without waiting; volatile order preserved
#define HLOAD(DA, DB, PTR)                                                       \
    asm volatile("global_load_dwordx4 %0, %2, off\n\t"                           \
                 "global_load_dwordx4 %1, %2, off offset:16"                     \
                 : "=&v"(DA), "=&v"(DB) : "v"(PTR))

template<bool TRANS>
__global__ __launch_bounds__(64, 1) void scan_wave(const float* __restrict__ cur,
        const float* __restrict__ Rm,   // Rt (TRANS) or R (fallback)
        const float* __restrict__ du_g, const float* __restrict__ dw_g,
        const float* __restrict__ a_g, const float* __restrict__ b_g,
        float* __restrict__ out) {
    const int lane = threadIdx.x & 63;
    const int b = blockIdx.x;
    const int n0 = lane << 3;            // 8 contiguous neurons per lane

    const float4 du0 = *(const float4*)(du_g + n0);
    const float4 du1 = *(const float4*)(du_g + n0 + 4);
    const float4 dw0 = *(const float4*)(dw_g + n0);
    const float4 dw1 = *(const float4*)(dw_g + n0 + 4);
    const float4 an0 = *(const float4*)(a_g + n0);
    const float4 an1 = *(const float4*)(a_g + n0 + 4);
    const float4 bn0 = *(const float4*)(b_g + n0);
    const float4 bn1 = *(const float4*)(b_g + n0 + 4);
    const float4 odu0 = {1.0f - du0.x, 1.0f - du0.y, 1.0f - du0.z, 1.0f - du0.w};
    const float4 odu1 = {1.0f - du1.x, 1.0f - du1.y, 1.0f - du1.z, 1.0f - du1.w};
    const float4 odw0 = {1.0f - dw0.x, 1.0f - dw0.y, 1.0f - dw0.z, 1.0f - dw0.w};
    const float4 odw1 = {1.0f - dw1.x, 1.0f - dw1.y, 1.0f - dw1.z, 1.0f - dw1.w};

    float4 u0 = {0,0,0,0}, u1 = {0,0,0,0};
    float4 w0 = {0,0,0,0}, w1 = {0,0,0,0};
    float4 z0 = {0,0,0,0}, z1 = {0,0,0,0};
    unsigned long long m0=0,m1=0,m2=0,m3=0,m4=0,m5=0,m6=0,m7=0;

    const float* curp = cur + (size_t)b * NT * NN + n0;   // == &cur[b][t][n0] at iter t
    float* outp = out + (size_t)b * NT * NN + n0;

    // 3-deep prefetch pipeline (named registers only)
    float4 pa0 = *(const float4*)(curp);
    float4 pa1 = *(const float4*)(curp + 4);
    float4 pb0 = *(const float4*)(curp + NN);
    float4 pb1 = *(const float4*)(curp + NN + 4);
    float4 pc0 = *(const float4*)(curp + 2 * NN);
    float4 pc1 = *(const float4*)(curp + 2 * NN + 4);

    for (int t = 0; t < NT; ++t) {
        float4 c0 = pa0, c1 = pa1;
        pa0 = pb0; pa1 = pb1;
        pb0 = pc0; pb1 = pc1;
        if (t + 3 < NT) {
            pc0 = *(const float4*)(curp + 3 * NN);
            pc1 = *(const float4*)(curp + 3 * NN + 4);
        }
        curp += NN;

        float4 r0 = {0,0,0,0}, r1 = {0,0,0,0};
        if (m0 | m1 | m2 | m3 | m4 | m5 | m6 | m7) {
            if (TRANS) {
                // ---- head addresses: first set bit of each mask (j=0 fallback) ----
                #define HEADJ(MM, E) ((MM) ? ((__builtin_ctzll(MM) << 3) + (E)) : 0)
                const float* hp0 = Rm + ((size_t)HEADJ(m0, 0) << 9) + n0;
                const float* hp1 = Rm + ((size_t)HEADJ(m1, 1) << 9) + n0;
                const float* hp2 = Rm + ((size_t)HEADJ(m2, 2) << 9) + n0;
                const float* hp3 = Rm + ((size_t)HEADJ(m3, 3) << 9) + n0;
                const float* hp4 = Rm + ((size_t)HEADJ(m4, 4) << 9) + n0;
                const float* hp5 = Rm + ((size_t)HEADJ(m5, 5) << 9) + n0;
                const float* hp6 = Rm + ((size_t)HEADJ(m6, 6) << 9) + n0;
                const float* hp7 = Rm + ((size_t)HEADJ(m7, 7) << 9) + n0;
                #undef HEADJ
                // ---- force all 16 loads into flight, then ONE wait ----
                f32x4 h0a, h0b, h1a, h1b, h2a, h2b, h3a, h3b;
                f32x4 h4a, h4b, h5a, h5b, h6a, h6b, h7a, h7b;
                HLOAD(h0a, h0b, hp0);
                HLOAD(h1a, h1b, hp1);
                HLOAD(h2a, h2b, hp2);
                HLOAD(h3a, h3b, hp3);
                HLOAD(h4a, h4b, hp4);
                HLOAD(h5a, h5b, hp5);
                HLOAD(h6a, h6b, hp6);
                HLOAD(h7a, h7b, hp7);
                asm volatile("s_waitcnt vmcnt(0)" ::: "memory");
                __builtin_amdgcn_sched_barrier(0);   // rule #18: stop use-hoisting

                #define ACC(QA, QB) do {                                          \
                    r0.x = __fadd_rn(r0.x, (QA).x); r0.y = __fadd_rn(r0.y, (QA).y);\
                    r0.z = __fadd_rn(r0.z, (QA).z); r0.w = __fadd_rn(r0.w, (QA).w);\
                    r1.x = __fadd_rn(r1.x, (QB).x); r1.y = __fadd_rn(r1.y, (QB).y);\
                    r1.z = __fadd_rn(r1.z, (QB).z); r1.w = __fadd_rn(r1.w, (QB).w);\
                } while (0)
                // ---- accumulate in the exact original order ----
                #define PROC(MM, E, HA, HB) do {                                  \
                    if (MM) {                                                     \
                        ACC(HA, HB);                                              \
                        unsigned long long g_ = (MM) & ((MM) - 1);                \
                        while (g_) {       /* rare: 2nd+ spike in same mask */    \
                            int l_ = __builtin_ctzll(g_); g_ &= g_ - 1;           \
                            int j_ = (l_ << 3) + (E);                             \
                            const float* rp_ = Rm + ((size_t)j_ << 9) + n0;       \
                            float4 q0_ = *(const float4*)rp_;                     \
                            float4 q1_ = *(const float4*)(rp_ + 4);               \
                            ACC(q0_, q1_);                                        \
                        }                                                         \
                    }                                                             \
                } while (0)
                PROC(m0, 0, h0a, h0b); PROC(m1, 1, h1a, h1b);
                PROC(m2, 2, h2a, h2b); PROC(m3, 3, h3a, h3b);
                PROC(m4, 4, h4a, h4b); PROC(m5, 5, h5a, h5b);
                PROC(m6, 6, h6a, h6b); PROC(m7, 7, h7a, h7b);
                #undef PROC
                #undef ACC
            } else {
                // fallback path (un-transposed R) — simple serial gather
                #define GATHER(MM, E) do {                                        \
                    unsigned long long g_ = (MM);                                 \
                    while (g_) {                                                  \
                        int l_ = __builtin_ctzll(g_); g_ &= g_ - 1;               \
                        int j_ = (l_ << 3) + (E);                                 \
                        float q0x_ = Rm[(size_t)(n0 + 0) * NN + j_];              \
                        float q0y_ = Rm[(size_t)(n0 + 1) * NN + j_];              \
                        float q0z_ = Rm[(size_t)(n0 + 2) * NN + j_];              \
                        float q0w_ = Rm[(size_t)(n0 + 3) * NN + j_];              \
                        float q1x_ = Rm[(size_t)(n0 + 4) * NN + j_];              \
                        float q1y_ = Rm[(size_t)(n0 + 5) * NN + j_];              \
                        float q1z_ = Rm[(size_t)(n0 + 6) * NN + j_];              \
                        float q1w_ = Rm[(size_t)(n0 + 7) * NN + j_];              \
                        r0.x = __fadd_rn(r0.x, q0x_); r0.y = __fadd_rn(r0.y, q0y_);\
                        r0.z = __fadd_rn(r0.z, q0z_); r0.w = __fadd_rn(r0.w, q0w_);\
                        r1.x = __fadd_rn(r1.x, q1x_); r1.y = __fadd_rn(r1.y, q1y_);\
                        r1.z = __fadd_rn(r1.z, q1z_); r1.w = __fadd_rn(r1.w, q1w_);\
                    }                                                             \
                } while (0)
                GATHER(m0, 0); GATHER(m1, 1); GATHER(m2, 2); GATHER(m3, 3);
                GATHER(m4, 4); GATHER(m5, 5); GATHER(m6, 6); GATHER(m7, 7);
                #undef GATHER
            }
        }

        UPD(c0.x, r0.x, du0.x, odu0.x, dw0.x, odw0.x, an0.x, bn0.x, u0.x, w0.x, z0.x);
        UPD(c0.y, r0.y, du0.y, odu0.y, dw0.y, odw0.y, an0.y, bn0.y, u0.y, w0.y, z0.y);
        UPD(c0.z, r0.z, du0.z, odu0.z, dw0.z, odw0.z, an0.z, bn0.z, u0.z, w0.z, z0.z);
        UPD(c0.w, r0.w, du0.w, odu0.w, dw0.w, odw0.w, an0.w, bn0.w, u0.w, w0.w, z0.w);
        UPD(c1.x, r1.x, du1.x, odu1.x, dw1.x, odw1.x, an1.x, bn1.x, u1.x, w1.x, z1.x);
        UPD(c1.y, r1.y, du1.y, odu1.y, dw1.y, odw1.y, an1.y, bn1.y, u1.y, w1.y, z1.y);
        UPD(c1.z, r1.z, du1.z, odu1.z, dw1.z, odw1.z, an1.z, bn1.z, u1.z, w1.z, z1.z);
        UPD(c1.w, r1.w, du1.w, odu1.w, dw1.w, odw1.w, an1.w, bn1.w, u1.w, w1.w, z1.w);

        // publish z_t as register bitmasks: m_e bit l <-> neuron l*8+e
        m0 = __ballot(z0.x > 0.5f);
        m1 = __ballot(z0.y > 0.5f);
        m2 = __ballot(z0.z > 0.5f);
        m3 = __ballot(z0.w > 0.5f);
        m4 = __ballot(z1.x > 0.5f);
        m5 = __ballot(z1.y > 0.5f);
        m6 = __ballot(z1.z > 0.5f);
        m7 = __ballot(z1.w > 0.5f);

        *(float4*)outp = z0;
        *(float4*)(outp + 4) = z1;
        outp += NN;
    }
}

extern "C" void kernel_launch(void* const* d_in, const int* in_sizes, int n_in,
                              void* d_out, int out_size, void* d_ws, size_t ws_size,
                              hipStream_t stream) {
    const float* x    = (const float*)d_in[0];   // [B,T,I]
    const float* W    = (const float*)d_in[1];   // [N,I]
    const float* bias = (const float*)d_in[2];   // [N]
    const float* R    = (const float*)d_in[3];   // [N,N]
    const float* du   = (const float*)d_in[4];
    const float* dw   = (const float*)d_in[5];
    const float* a    = (const float*)d_in[6];
    const float* b    = (const float*)d_in[7];
    float* out = (float*)d_out;                  // [B,T,N] fp32 spikes

    const size_t curBytes = (size_t)M_TOT * NN * sizeof(float);   // 131 MB
    const size_t rtBytes  = (size_t)NN * NN * sizeof(float);      // 1 MB
    float* Rt  = nullptr;
    float* cur;
    if (ws_size >= rtBytes + curBytes) {
        Rt  = (float*)d_ws;
        cur = (float*)d_ws + (size_t)NN * NN;
    } else if (ws_size >= rtBytes) {
        Rt  = (float*)d_ws;
        cur = out;          // read-before-overwrite per element is safe
    } else {
        cur = out;
    }

    if (Rt) {
        transpose_R<<<(NN * NN + 255) / 256, 256, 0, stream>>>(R, Rt);
    }
    dim3 ggrid(M_TOT / GBM, NN / GBN);
    gemm_xw<<<ggrid, 256, 0, stream>>>(x, W, bias, cur);
    if (Rt) {
        scan_wave<true><<<NB, 64, 0, stream>>>(cur, Rt, du, dw, a, b, out);
    } else {
        scan_wave<false><<<NB, 64, 0, stream>>>(cur, R, du, dw, a, b, out);
    }
}

// Round 12
// 1113.342 us; speedup vs baseline: 1.2956x; 1.2956x over previous
//
#include <hip/hip_runtime.h>
#include <cstdint>
#include <cstddef>

#define NB 32      // batch
#define NT 2000    // timesteps
#define NI 256     // input dim
#define NN 512     // neurons
#define M_TOT (NB * NT)   // 64000 rows of the input GEMM
#define DS 8       // LDS cur ring slots

typedef float f32x4 __attribute__((ext_vector_type(4)));

// ---------------- transpose R -> Rt (Rt[j][n] = R[n][j]) ----------------
__global__ void transpose_R(const float* __restrict__ R, float* __restrict__ Rt) {
    int idx = blockIdx.x * blockDim.x + threadIdx.x;
    if (idx >= NN * NN) return;
    int j = idx >> 9;
    int n = idx & (NN - 1);
    Rt[idx] = R[n * NN + j];
}

// ---------------- GEMM: cur[m][n] = sum_k x[m][k]*W[n][k] + bias[n] ----------------
#define GBM 128
#define GBN 128
#define GBK 16
__global__ __launch_bounds__(256) void gemm_xw(const float* __restrict__ A,
                                               const float* __restrict__ Wt,
                                               const float* __restrict__ bias,
                                               float* __restrict__ C) {
    __shared__ float As[GBK][GBM];
    __shared__ float Bs[GBK][GBN];
    const int tid = threadIdx.x;
    const int bm = blockIdx.x * GBM;
    const int bn = blockIdx.y * GBN;
    const int tx = tid & 15, ty = tid >> 4;
    const int lrow = tid >> 1;
    const int lk = (tid & 1) * 8;
    float acc[8][8] = {};
    const float* Arow = A + (size_t)(bm + lrow) * NI + lk;
    const float* Brow = Wt + (size_t)(bn + lrow) * NI + lk;
    for (int k0 = 0; k0 < NI; k0 += GBK) {
        float4 a0 = *(const float4*)(Arow + k0);
        float4 a1 = *(const float4*)(Arow + k0 + 4);
        float4 b0 = *(const float4*)(Brow + k0);
        float4 b1 = *(const float4*)(Brow + k0 + 4);
        __syncthreads();
        As[lk + 0][lrow] = a0.x; As[lk + 1][lrow] = a0.y;
        As[lk + 2][lrow] = a0.z; As[lk + 3][lrow] = a0.w;
        As[lk + 4][lrow] = a1.x; As[lk + 5][lrow] = a1.y;
        As[lk + 6][lrow] = a1.z; As[lk + 7][lrow] = a1.w;
        Bs[lk + 0][lrow] = b0.x; Bs[lk + 1][lrow] = b0.y;
        Bs[lk + 2][lrow] = b0.z; Bs[lk + 3][lrow] = b0.w;
        Bs[lk + 4][lrow] = b1.x; Bs[lk + 5][lrow] = b1.y;
        Bs[lk + 6][lrow] = b1.z; Bs[lk + 7][lrow] = b1.w;
        __syncthreads();
        #pragma unroll
        for (int k = 0; k < GBK; ++k) {
            float4 av0 = *(const float4*)&As[k][ty * 8];
            float4 av1 = *(const float4*)&As[k][ty * 8 + 4];
            float4 bv0 = *(const float4*)&Bs[k][tx * 8];
            float4 bv1 = *(const float4*)&Bs[k][tx * 8 + 4];
            float a_[8] = {av0.x, av0.y, av0.z, av0.w, av1.x, av1.y, av1.z, av1.w};
            float b_[8] = {bv0.x, bv0.y, bv0.z, bv0.w, bv1.x, bv1.y, bv1.z, bv1.w};
            #pragma unroll
            for (int i = 0; i < 8; ++i)
                #pragma unroll
                for (int j = 0; j < 8; ++j)
                    acc[i][j] += a_[i] * b_[j];
        }
    }
    #pragma unroll
    for (int i = 0; i < 8; ++i) {
        const int row = bm + ty * 8 + i;
        #pragma unroll
        for (int j = 0; j < 8; ++j) {
            const int col = bn + tx * 8 + j;
            C[(size_t)row * NN + col] = acc[i][j] + bias[col];
        }
    }
}

// ---------------- producer/consumer LIF scan: 2 waves per batch element ----------------
// Producer (wave 1) stages cur through an 8-slot LDS ring; consumer (wave 0)
// computes the scan. cur consumption moves to the lgkmcnt domain, so the
// consumer's vmcnt FIFO holds ONLY gather loads (+old stores): the asm-forced
// head loads' vmcnt(0) is a single ~200cy L2 round trip, no HBM prefetch drain.
// Arithmetic identical to the passing kernels (e=0..7, ascending-bit adds).

#define UPD(C_, R_, DU_, ODU_, DW_, ODW_, A_, B_, U_, W_, Z_) do {               \
    float cc_   = __fadd_rn((C_), (R_));                                         \
    float unew_ = __fadd_rn(__fmul_rn((DU_), (U_)),                              \
                            __fmul_rn((ODU_), __fsub_rn(cc_, (W_))));            \
    float zn_   = (__fsub_rn(unew_, 1.0f) > 0.0f) ? 1.0f : 0.0f;                 \
    float s_    = __fadd_rn(__fmul_rn((A_), (U_)), __fmul_rn((B_), (Z_)));       \
    float wnew_ = __fadd_rn(__fmul_rn((DW_), (W_)),                              \
                            __fmul_rn(__fmul_rn((ODW_), s_), 120.0f));           \
    (U_) = __fmul_rn(unew_, __fsub_rn(1.0f, zn_));                               \
    (W_) = wnew_;                                                                \
    (Z_) = zn_;                                                                  \
} while (0)

#define HLOAD(DA, DB, PTR)                                                       \
    asm volatile("global_load_dwordx4 %0, %2, off\n\t"                           \
                 "global_load_dwordx4 %1, %2, off offset:16"                     \
                 : "=&v"(DA), "=&v"(DB) : "v"(PTR))

__global__ __launch_bounds__(128, 1) void scan_pc(const float* __restrict__ cur,
        const float* __restrict__ Rm,   // Rt: Rm[j][n] = R[n][j]
        const float* __restrict__ du_g, const float* __restrict__ dw_g,
        const float* __restrict__ a_g, const float* __restrict__ b_g,
        float* __restrict__ out) {
    __shared__ float curlds[DS][NN];   // 16 KB ring of cur rows
    const int tid = threadIdx.x;
    const int lane = tid & 63;
    const int b = blockIdx.x;
    const float* curb = cur + (size_t)b * NT * NN;

    if (tid >= 64) {
        // ================= producer wave =================
        const int off = lane << 3;          // 8 floats per lane covers the 512-row
        float4 q0a, q0b, q1a, q1b, q2a, q2b, q3a, q3b;
        #define PLOAD(QA, QB, STEP) do {                                          \
            const float* p_ = curb + (size_t)(STEP) * NN + off;                   \
            QA = *(const float4*)p_; QB = *(const float4*)(p_ + 4);               \
        } while (0)
        #define PSTORE(QA, QB, STEP) do {                                         \
            int sl_ = (STEP) & (DS - 1);                                          \
            *(float4*)&curlds[sl_][off] = QA;                                     \
            *(float4*)&curlds[sl_][off + 4] = QB;                                 \
        } while (0)
        // prologue: slots 0..2 written; queue holds steps 3,4,5,6
        PLOAD(q0a, q0b, 0); PLOAD(q1a, q1b, 1); PLOAD(q2a, q2b, 2); PLOAD(q3a, q3b, 3);
        PSTORE(q0a, q0b, 0); PSTORE(q1a, q1b, 1); PSTORE(q2a, q2b, 2);
        PLOAD(q0a, q0b, 4); PLOAD(q1a, q1b, 5); PLOAD(q2a, q2b, 6);
        #define PSTEP(QA, QB, T) do {                                             \
            int ws_ = (T) + 3; if (ws_ > NT - 1) ws_ = NT - 1;                    \
            int ls_ = (T) + 7; if (ls_ > NT - 1) ls_ = NT - 1;                    \
            PSTORE(QA, QB, ws_);                                                  \
            PLOAD(QA, QB, ls_);                                                   \
            asm volatile("s_waitcnt lgkmcnt(0)" ::: "memory");                    \
            __builtin_amdgcn_s_barrier();                                         \
        } while (0)
        for (int t = 0; t < NT; t += 4) {   // NT % 4 == 0; q index = (t+3)&3
            PSTEP(q3a, q3b, t + 0);
            PSTEP(q0a, q0b, t + 1);
            PSTEP(q1a, q1b, t + 2);
            PSTEP(q2a, q2b, t + 3);
        }
        #undef PSTEP
        #undef PSTORE
        #undef PLOAD
    } else {
        // ================= consumer wave =================
        const int n0 = lane << 3;

        const float4 du0 = *(const float4*)(du_g + n0);
        const float4 du1 = *(const float4*)(du_g + n0 + 4);
        const float4 dw0 = *(const float4*)(dw_g + n0);
        const float4 dw1 = *(const float4*)(dw_g + n0 + 4);
        const float4 an0 = *(const float4*)(a_g + n0);
        const float4 an1 = *(const float4*)(a_g + n0 + 4);
        const float4 bn0 = *(const float4*)(b_g + n0);
        const float4 bn1 = *(const float4*)(b_g + n0 + 4);
        const float4 odu0 = {1.0f - du0.x, 1.0f - du0.y, 1.0f - du0.z, 1.0f - du0.w};
        const float4 odu1 = {1.0f - du1.x, 1.0f - du1.y, 1.0f - du1.z, 1.0f - du1.w};
        const float4 odw0 = {1.0f - dw0.x, 1.0f - dw0.y, 1.0f - dw0.z, 1.0f - dw0.w};
        const float4 odw1 = {1.0f - dw1.x, 1.0f - dw1.y, 1.0f - dw1.z, 1.0f - dw1.w};

        float4 u0 = {0,0,0,0}, u1 = {0,0,0,0};
        float4 w0 = {0,0,0,0}, w1 = {0,0,0,0};
        float4 z0 = {0,0,0,0}, z1 = {0,0,0,0};
        unsigned long long m0=0,m1=0,m2=0,m3=0,m4=0,m5=0,m6=0,m7=0;

        float* outp = out + (size_t)b * NT * NN + n0;

        for (int t = 0; t < NT; ++t) {
            __builtin_amdgcn_s_barrier();
            __builtin_amdgcn_sched_barrier(0);   // pin: no motion across barrier
            asm volatile("" ::: "memory");
            const int slot = t & (DS - 1);
            float4 c0 = *(const float4*)&curlds[slot][n0];
            float4 c1 = *(const float4*)&curlds[slot][n0 + 4];

            float4 r0 = {0,0,0,0}, r1 = {0,0,0,0};
            if (m0 | m1 | m2 | m3 | m4 | m5 | m6 | m7) {
                #define HEADJ(MM, E) ((MM) ? ((__builtin_ctzll(MM) << 3) + (E)) : 0)
                const float* hp0 = Rm + ((size_t)HEADJ(m0, 0) << 9) + n0;
                const float* hp1 = Rm + ((size_t)HEADJ(m1, 1) << 9) + n0;
                const float* hp2 = Rm + ((size_t)HEADJ(m2, 2) << 9) + n0;
                const float* hp3 = Rm + ((size_t)HEADJ(m3, 3) << 9) + n0;
                const float* hp4 = Rm + ((size_t)HEADJ(m4, 4) << 9) + n0;
                const float* hp5 = Rm + ((size_t)HEADJ(m5, 5) << 9) + n0;
                const float* hp6 = Rm + ((size_t)HEADJ(m6, 6) << 9) + n0;
                const float* hp7 = Rm + ((size_t)HEADJ(m7, 7) << 9) + n0;
                #undef HEADJ
                f32x4 h0a, h0b, h1a, h1b, h2a, h2b, h3a, h3b;
                f32x4 h4a, h4b, h5a, h5b, h6a, h6b, h7a, h7b;
                HLOAD(h0a, h0b, hp0);
                HLOAD(h1a, h1b, hp1);
                HLOAD(h2a, h2b, hp2);
                HLOAD(h3a, h3b, hp3);
                HLOAD(h4a, h4b, hp4);
                HLOAD(h5a, h5b, hp5);
                HLOAD(h6a, h6b, hp6);
                HLOAD(h7a, h7b, hp7);
                // only gather loads (+retired old stores) in this wave's vmcnt
                asm volatile("s_waitcnt vmcnt(0)" ::: "memory");
                __builtin_amdgcn_sched_barrier(0);

                #define ACC(QA, QB) do {                                          \
                    r0.x = __fadd_rn(r0.x, (QA).x); r0.y = __fadd_rn(r0.y, (QA).y);\
                    r0.z = __fadd_rn(r0.z, (QA).z); r0.w = __fadd_rn(r0.w, (QA).w);\
                    r1.x = __fadd_rn(r1.x, (QB).x); r1.y = __fadd_rn(r1.y, (QB).y);\
                    r1.z = __fadd_rn(r1.z, (QB).z); r1.w = __fadd_rn(r1.w, (QB).w);\
                } while (0)
                #define PROC(MM, E, HA, HB) do {                                  \
                    if (MM) {                                                     \
                        ACC(HA, HB);                                              \
                        unsigned long long g_ = (MM) & ((MM) - 1);                \
                        while (g_) {                                              \
                            int l_ = __builtin_ctzll(g_); g_ &= g_ - 1;           \
                            int j_ = (l_ << 3) + (E);                             \
                            const float* rp_ = Rm + ((size_t)j_ << 9) + n0;       \
                            float4 q0_ = *(const float4*)rp_;                     \
                            float4 q1_ = *(const float4*)(rp_ + 4);               \
                            ACC(q0_, q1_);                                        \
                        }                                                         \
                    }                                                             \
                } while (0)
                PROC(m0, 0, h0a, h0b); PROC(m1, 1, h1a, h1b);
                PROC(m2, 2, h2a, h2b); PROC(m3, 3, h3a, h3b);
                PROC(m4, 4, h4a, h4b); PROC(m5, 5, h5a, h5b);
                PROC(m6, 6, h6a, h6b); PROC(m7, 7, h7a, h7b);
                #undef PROC
                #undef ACC
            }

            UPD(c0.x, r0.x, du0.x, odu0.x, dw0.x, odw0.x, an0.x, bn0.x, u0.x, w0.x, z0.x);
            UPD(c0.y, r0.y, du0.y, odu0.y, dw0.y, odw0.y, an0.y, bn0.y, u0.y, w0.y, z0.y);
            UPD(c0.z, r0.z, du0.z, odu0.z, dw0.z, odw0.z, an0.z, bn0.z, u0.z, w0.z, z0.z);
            UPD(c0.w, r0.w, du0.w, odu0.w, dw0.w, odw0.w, an0.w, bn0.w, u0.w, w0.w, z0.w);
            UPD(c1.x, r1.x, du1.x, odu1.x, dw1.x, odw1.x, an1.x, bn1.x, u1.x, w1.x, z1.x);
            UPD(c1.y, r1.y, du1.y, odu1.y, dw1.y, odw1.y, an1.y, bn1.y, u1.y, w1.y, z1.y);
            UPD(c1.z, r1.z, du1.z, odu1.z, dw1.z, odw1.z, an1.z, bn1.z, u1.z, w1.z, z1.z);
            UPD(c1.w, r1.w, du1.w, odu1.w, dw1.w, odw1.w, an1.w, bn1.w, u1.w, w1.w, z1.w);

            m0 = __ballot(z0.x > 0.5f);
            m1 = __ballot(z0.y > 0.5f);
            m2 = __ballot(z0.z > 0.5f);
            m3 = __ballot(z0.w > 0.5f);
            m4 = __ballot(z1.x > 0.5f);
            m5 = __ballot(z1.y > 0.5f);
            m6 = __ballot(z1.z > 0.5f);
            m7 = __ballot(z1.w > 0.5f);

            *(float4*)outp = z0;
            *(float4*)(outp + 4) = z1;
            outp += NN;
        }
    }
}

// ---------------- fallback scan (un-transposed R; only if workspace tiny) --------
__global__ __launch_bounds__(64) void scan_fallback(const float* __restrict__ cur,
        const float* __restrict__ Rm,
        const float* __restrict__ du_g, const float* __restrict__ dw_g,
        const float* __restrict__ a_g, const float* __restrict__ b_g,
        float* __restrict__ out) {
    const int lane = threadIdx.x & 63;
    const int b = blockIdx.x;
    const int n0 = lane << 3;
    const float4 du0 = *(const float4*)(du_g + n0);
    const float4 du1 = *(const float4*)(du_g + n0 + 4);
    const float4 dw0 = *(const float4*)(dw_g + n0);
    const float4 dw1 = *(const float4*)(dw_g + n0 + 4);
    const float4 an0 = *(const float4*)(a_g + n0);
    const float4 an1 = *(const float4*)(a_g + n0 + 4);
    const float4 bn0 = *(const float4*)(b_g + n0);
    const float4 bn1 = *(const float4*)(b_g + n0 + 4);
    const float4 odu0 = {1.0f - du0.x, 1.0f - du0.y, 1.0f - du0.z, 1.0f - du0.w};
    const float4 odu1 = {1.0f - du1.x, 1.0f - du1.y, 1.0f - du1.z, 1.0f - du1.w};
    const float4 odw0 = {1.0f - dw0.x, 1.0f - dw0.y, 1.0f - dw0.z, 1.0f - dw0.w};
    const float4 odw1 = {1.0f - dw1.x, 1.0f - dw1.y, 1.0f - dw1.z, 1.0f - dw1.w};
    float4 u0 = {0,0,0,0}, u1 = {0,0,0,0};
    float4 w0 = {0,0,0,0}, w1 = {0,0,0,0};
    float4 z0 = {0,0,0,0}, z1 = {0,0,0,0};
    unsigned long long m0=0,m1=0,m2=0,m3=0,m4=0,m5=0,m6=0,m7=0;
    const float* curp = cur + (size_t)b * NT * NN + n0;
    float* outp = out + (size_t)b * NT * NN + n0;
    for (int t = 0; t < NT; ++t) {
        float4 c0 = *(const float4*)(curp);
        float4 c1 = *(const float4*)(curp + 4);
        curp += NN;
        float4 r0 = {0,0,0,0}, r1 = {0,0,0,0};
        #define GATHER(MM, E) do {                                                \
            unsigned long long g_ = (MM);                                         \
            while (g_) {                                                          \
                int l_ = __builtin_ctzll(g_); g_ &= g_ - 1;                       \
                int j_ = (l_ << 3) + (E);                                         \
                float q0x_ = Rm[(size_t)(n0 + 0) * NN + j_];                      \
                float q0y_ = Rm[(size_t)(n0 + 1) * NN + j_];                      \
                float q0z_ = Rm[(size_t)(n0 + 2) * NN + j_];                      \
                float q0w_ = Rm[(size_t)(n0 + 3) * NN + j_];                      \
                float q1x_ = Rm[(size_t)(n0 + 4) * NN + j_];                      \
                float q1y_ = Rm[(size_t)(n0 + 5) * NN + j_];                      \
                float q1z_ = Rm[(size_t)(n0 + 6) * NN + j_];                      \
                float q1w_ = Rm[(size_t)(n0 + 7) * NN + j_];                      \
                r0.x = __fadd_rn(r0.x, q0x_); r0.y = __fadd_rn(r0.y, q0y_);       \
                r0.z = __fadd_rn(r0.z, q0z_); r0.w = __fadd_rn(r0.w, q0w_);       \
                r1.x = __fadd_rn(r1.x, q1x_); r1.y = __fadd_rn(r1.y, q1y_);       \
                r1.z = __fadd_rn(r1.z, q1z_); r1.w = __fadd_rn(r1.w, q1w_);       \
            }                                                                     \
        } while (0)
        GATHER(m0, 0); GATHER(m1, 1); GATHER(m2, 2); GATHER(m3, 3);
        GATHER(m4, 4); GATHER(m5, 5); GATHER(m6, 6); GATHER(m7, 7);
        #undef GATHER
        UPD(c0.x, r0.x, du0.x, odu0.x, dw0.x, odw0.x, an0.x, bn0.x, u0.x, w0.x, z0.x);
        UPD(c0.y, r0.y, du0.y, odu0.y, dw0.y, odw0.y, an0.y, bn0.y, u0.y, w0.y, z0.y);
        UPD(c0.z, r0.z, du0.z, odu0.z, dw0.z, odw0.z, an0.z, bn0.z, u0.z, w0.z, z0.z);
        UPD(c0.w, r0.w, du0.w, odu0.w, dw0.w, odw0.w, an0.w, bn0.w, u0.w, w0.w, z0.w);
        UPD(c1.x, r1.x, du1.x, odu1.x, dw1.x, odw1.x, an1.x, bn1.x, u1.x, w1.x, z1.x);
        UPD(c1.y, r1.y, du1.y, odu1.y, dw1.y, odw1.y, an1.y, bn1.y, u1.y, w1.y, z1.y);
        UPD(c1.z, r1.z, du1.z, odu1.z, dw1.z, odw1.z, an1.z, bn1.z, u1.z, w1.z, z1.z);
        UPD(c1.w, r1.w, du1.w, odu1.w, dw1.w, odw1.w, an1.w, bn1.w, u1.w, w1.w, z1.w);
        m0 = __ballot(z0.x > 0.5f);
        m1 = __ballot(z0.y > 0.5f);
        m2 = __ballot(z0.z > 0.5f);
        m3 = __ballot(z0.w > 0.5f);
        m4 = __ballot(z1.x > 0.5f);
        m5 = __ballot(z1.y > 0.5f);
        m6 = __ballot(z1.z > 0.5f);
        m7 = __ballot(z1.w > 0.5f);
        *(float4*)outp = z0;
        *(float4*)(outp + 4) = z1;
        outp += NN;
    }
}

extern "C" void kernel_launch(void* const* d_in, const int* in_sizes, int n_in,
                              void* d_out, int out_size, void* d_ws, size_t ws_size,
                              hipStream_t stream) {
    const float* x    = (const float*)d_in[0];
    const float* W    = (const float*)d_in[1];
    const float* bias = (const float*)d_in[2];
    const float* R    = (const float*)d_in[3];
    const float* du   = (const float*)d_in[4];
    const float* dw   = (const float*)d_in[5];
    const float* a    = (const float*)d_in[6];
    const float* b    = (const float*)d_in[7];
    float* out = (float*)d_out;

    const size_t curBytes = (size_t)M_TOT * NN * sizeof(float);   // 131 MB
    const size_t rtBytes  = (size_t)NN * NN * sizeof(float);      // 1 MB
    float* Rt  = nullptr;
    float* cur;
    if (ws_size >= rtBytes + curBytes) {
        Rt  = (float*)d_ws;
        cur = (float*)d_ws + (size_t)NN * NN;
    } else if (ws_size >= rtBytes) {
        Rt  = (float*)d_ws;
        cur = out;
    } else {
        cur = out;
    }

    if (Rt) {
        transpose_R<<<(NN * NN + 255) / 256, 256, 0, stream>>>(R, Rt);
    }
    dim3 ggrid(M_TOT / GBM, NN / GBN);
    gemm_xw<<<ggrid, 256, 0, stream>>>(x, W, bias, cur);
    if (Rt) {
        scan_pc<<<NB, 128, 0, stream>>>(cur, Rt, du, dw, a, b, out);
    } else {
        scan_fallback<<<NB, 64, 0, stream>>>(cur, R, du, dw, a, b, out);
    }
}